// Round 1
// baseline (4740.166 us; speedup 1.0000x reference)
//
#include <hip/hip_runtime.h>
#include <hip/hip_bf16.h>

constexpr int kDim   = 1536;
constexpr int kHeads = 12;
constexpr int kHd    = 128;
constexpr int kS     = 3072;
constexpr int kB     = 2;
constexpr float kEps   = 1e-6f;
constexpr float kScale = 0.08838834764831845f; // 1/sqrt(128)

// ---------------------------------------------------------------------------
// GEMM: C[M][N] = X[M][K] @ W[N][K]^T + bias[N]
// 128x128 tile, BK=16, 256 threads, 8x8 micro-tile per thread.
// ---------------------------------------------------------------------------
constexpr int GBK = 16, GPAD = 132;

__global__ __launch_bounds__(256)
void gemm_bt_kernel(const float* __restrict__ X, const float* __restrict__ W,
                    const float* __restrict__ bias, float* __restrict__ C,
                    int M, int N, int K)
{
    __shared__ float As[GBK][GPAD];
    __shared__ float Bs[GBK][GPAD];
    const int t  = threadIdx.x;
    const int tx = t & 15;
    const int ty = t >> 4;
    const int m0 = blockIdx.y * 128;
    const int n0 = blockIdx.x * 128;

    const int lrow = t >> 2;        // 0..63
    const int lc   = (t & 3) * 4;   // 0,4,8,12

    const float* Ap = X + (size_t)(m0 + lrow) * K + lc;
    const float* Bp = W + (size_t)(n0 + lrow) * K + lc;
    const size_t half = (size_t)64 * K;

    float acc[8][8];
    #pragma unroll
    for (int i = 0; i < 8; ++i)
        #pragma unroll
        for (int j = 0; j < 8; ++j) acc[i][j] = 0.f;

    for (int k0 = 0; k0 < K; k0 += GBK) {
        float4 a0 = *reinterpret_cast<const float4*>(Ap + k0);
        float4 a1 = *reinterpret_cast<const float4*>(Ap + half + k0);
        float4 b0 = *reinterpret_cast<const float4*>(Bp + k0);
        float4 b1 = *reinterpret_cast<const float4*>(Bp + half + k0);
        __syncthreads();
        As[lc+0][lrow] = a0.x; As[lc+1][lrow] = a0.y; As[lc+2][lrow] = a0.z; As[lc+3][lrow] = a0.w;
        As[lc+0][lrow+64] = a1.x; As[lc+1][lrow+64] = a1.y; As[lc+2][lrow+64] = a1.z; As[lc+3][lrow+64] = a1.w;
        Bs[lc+0][lrow] = b0.x; Bs[lc+1][lrow] = b0.y; Bs[lc+2][lrow] = b0.z; Bs[lc+3][lrow] = b0.w;
        Bs[lc+0][lrow+64] = b1.x; Bs[lc+1][lrow+64] = b1.y; Bs[lc+2][lrow+64] = b1.z; Bs[lc+3][lrow+64] = b1.w;
        __syncthreads();
        #pragma unroll
        for (int k = 0; k < GBK; ++k) {
            const float4* ar = reinterpret_cast<const float4*>(&As[k][0]);
            const float4* br = reinterpret_cast<const float4*>(&Bs[k][0]);
            float4 am0 = ar[ty*2], am1 = ar[ty*2+1];
            float4 bn0 = br[tx],   bn1 = br[tx+16];
            float a[8] = {am0.x,am0.y,am0.z,am0.w,am1.x,am1.y,am1.z,am1.w};
            float b[8] = {bn0.x,bn0.y,bn0.z,bn0.w,bn1.x,bn1.y,bn1.z,bn1.w};
            #pragma unroll
            for (int i = 0; i < 8; ++i)
                #pragma unroll
                for (int j = 0; j < 8; ++j)
                    acc[i][j] = fmaf(a[i], b[j], acc[i][j]);
        }
    }

    #pragma unroll
    for (int i = 0; i < 8; ++i) {
        const size_t m = (size_t)(m0 + ty*8 + i);
        float4 o0, o1;
        o0.x = acc[i][0] + bias[n0 + tx*4 + 0];
        o0.y = acc[i][1] + bias[n0 + tx*4 + 1];
        o0.z = acc[i][2] + bias[n0 + tx*4 + 2];
        o0.w = acc[i][3] + bias[n0 + tx*4 + 3];
        o1.x = acc[i][4] + bias[n0 + 64 + tx*4 + 0];
        o1.y = acc[i][5] + bias[n0 + 64 + tx*4 + 1];
        o1.z = acc[i][6] + bias[n0 + 64 + tx*4 + 2];
        o1.w = acc[i][7] + bias[n0 + 64 + tx*4 + 3];
        *reinterpret_cast<float4*>(C + m * N + n0 + tx*4)      = o0;
        *reinterpret_cast<float4*>(C + m * N + n0 + 64 + tx*4) = o1;
    }
}

// ---------------------------------------------------------------------------
// Fused RMSNorm (over full 1536) + RoPE (per head, interleaved pairs).
// One block per (row, which) ; which: 0=q, 1=k.
// ---------------------------------------------------------------------------
__global__ __launch_bounds__(256)
void rmsrope_kernel(float* __restrict__ qbuf, float* __restrict__ kbuf,
                    const float* __restrict__ gq, const float* __restrict__ gk,
                    const float* __restrict__ freqs, const int* __restrict__ grid_sizes)
{
    __shared__ float buf[kDim];
    __shared__ float red[8];
    const int row   = blockIdx.x;
    const int which = blockIdx.y;
    float* ptr = (which == 0 ? qbuf : kbuf) + (size_t)row * kDim;
    const float* g = (which == 0) ? gq : gk;
    const int t = threadIdx.x;

    float ss = 0.f;
    #pragma unroll
    for (int i = 0; i < kDim/256; ++i) {
        float v_ = ptr[t + i*256];
        buf[t + i*256] = v_;
        ss += v_*v_;
    }
    #pragma unroll
    for (int off = 32; off >= 1; off >>= 1) ss += __shfl_down(ss, off);
    if ((t & 63) == 0) red[t >> 6] = ss;
    __syncthreads();
    if (t == 0) red[4] = rsqrtf((red[0]+red[1]+red[2]+red[3]) * (1.f/kDim) + kEps);
    __syncthreads();
    const float scale = red[4];

    const int b = row / kS, s = row % kS;
    const int gh = grid_sizes[b*3+1], gw = grid_sizes[b*3+2];
    const int hw = gh * gw;
    const int fi  = s / hw;
    const int rem = s - fi*hw;
    const int hi  = rem / gw;
    const int wi  = rem - hi*gw;

    #pragma unroll
    for (int i = 0; i < (kDim/2)/256; ++i) {
        int p = t + i*256;
        int c = p & 63;                         // pair index within head (C=64)
        int pos = (c < 22) ? fi : (c < 43 ? hi : wi);   // s0=22, s0+s1=43
        float ang = freqs[pos*64 + c];
        float sn, cs;
        sincosf(ang, &sn, &cs);
        float e0 = buf[2*p]   * scale * g[2*p];
        float e1 = buf[2*p+1] * scale * g[2*p+1];
        float2 o;
        o.x = e0*cs - e1*sn;
        o.y = e0*sn + e1*cs;
        *reinterpret_cast<float2*>(ptr + 2*p) = o;
    }
}

// ---------------------------------------------------------------------------
// Flash attention, fp32. 32 q-rows per block, 256 threads.
// Each row owned by an 8-lane group (t>>3 = row, t&7 = lane-in-group).
// ---------------------------------------------------------------------------
__global__ __launch_bounds__(256)
void attn_kernel(const float* __restrict__ q, const float* __restrict__ k,
                 const float* __restrict__ v, float* __restrict__ o,
                 const int* __restrict__ seq_lens)
{
    __shared__ float Qs[32][132];
    __shared__ float Ks[32][132];
    __shared__ float Vs[32][132];
    __shared__ float Ss[32][33];

    const int t  = threadIdx.x;
    const int qt = blockIdx.x;
    const int h  = blockIdx.y;
    const int b  = blockIdx.z;
    const int seq = seq_lens[b];
    const int q0 = qt * 32;

    const int r  = t >> 3;
    const int gg = t & 7;

    {
        const float4* s4 = reinterpret_cast<const float4*>(
            q + (size_t)(b*kS + q0 + r) * kDim + h*kHd);
        float4* d4 = reinterpret_cast<float4*>(&Qs[r][0]);
        #pragma unroll
        for (int j = 0; j < 4; ++j) d4[gg + 8*j] = s4[gg + 8*j];
    }

    float4 o4[4];
    #pragma unroll
    for (int jj = 0; jj < 4; ++jj) o4[jj] = make_float4(0.f,0.f,0.f,0.f);
    float m_run = -1e30f, l_run = 0.f;

    const float* kbase = k + (size_t)(b*kS)*kDim + h*kHd;
    const float* vbase = v + (size_t)(b*kS)*kDim + h*kHd;

    for (int kt = 0; kt < kS/32; ++kt) {
        const int k0 = kt*32;
        __syncthreads();   // previous PV done reading Vs/Ss
        {
            const float4* s4 = reinterpret_cast<const float4*>(kbase + (size_t)(k0 + r)*kDim);
            float4* d4 = reinterpret_cast<float4*>(&Ks[r][0]);
            #pragma unroll
            for (int j = 0; j < 4; ++j) d4[gg + 8*j] = s4[gg + 8*j];
            const float4* s4v = reinterpret_cast<const float4*>(vbase + (size_t)(k0 + r)*kDim);
            float4* d4v = reinterpret_cast<float4*>(&Vs[r][0]);
            #pragma unroll
            for (int j = 0; j < 4; ++j) d4v[gg + 8*j] = s4v[gg + 8*j];
        }
        __syncthreads();

        // ---- scores: row r, cols gg + 8j ----
        float sc[4] = {0.f,0.f,0.f,0.f};
        {
            const float4* qrow = reinterpret_cast<const float4*>(&Qs[r][0]);
            const float4* kr0 = reinterpret_cast<const float4*>(&Ks[gg][0]);
            const float4* kr1 = reinterpret_cast<const float4*>(&Ks[gg+8][0]);
            const float4* kr2 = reinterpret_cast<const float4*>(&Ks[gg+16][0]);
            const float4* kr3 = reinterpret_cast<const float4*>(&Ks[gg+24][0]);
            #pragma unroll 8
            for (int x = 0; x < 32; ++x) {
                float4 qv = qrow[x];
                float4 a = kr0[x], bb = kr1[x], c = kr2[x], d = kr3[x];
                sc[0] += qv.x*a.x  + qv.y*a.y  + qv.z*a.z  + qv.w*a.w;
                sc[1] += qv.x*bb.x + qv.y*bb.y + qv.z*bb.z + qv.w*bb.w;
                sc[2] += qv.x*c.x  + qv.y*c.y  + qv.z*c.z  + qv.w*c.w;
                sc[3] += qv.x*d.x  + qv.y*d.y  + qv.z*d.z  + qv.w*d.w;
            }
        }
        #pragma unroll
        for (int j = 0; j < 4; ++j) {
            sc[j] *= kScale;
            if (k0 + gg + 8*j >= seq) sc[j] = -1e30f;
        }

        // ---- online softmax (8-lane group per row) ----
        float rowmax = fmaxf(fmaxf(sc[0], sc[1]), fmaxf(sc[2], sc[3]));
        #pragma unroll
        for (int msk = 1; msk < 8; msk <<= 1)
            rowmax = fmaxf(rowmax, __shfl_xor(rowmax, msk));
        const float m_new = fmaxf(m_run, rowmax);
        const float alpha = expf(m_run - m_new);
        float rsum = 0.f;
        #pragma unroll
        for (int j = 0; j < 4; ++j) {
            float p = expf(sc[j] - m_new);
            Ss[r][gg + 8*j] = p;
            rsum += p;
        }
        #pragma unroll
        for (int msk = 1; msk < 8; msk <<= 1) rsum += __shfl_xor(rsum, msk);
        l_run = l_run * alpha + rsum;
        m_run = m_new;
        __syncthreads();   // Ss visible to whole block

        // ---- PV accumulate: row r, d-quads at 4*gg + 32*jj ----
        #pragma unroll
        for (int jj = 0; jj < 4; ++jj) {
            o4[jj].x *= alpha; o4[jj].y *= alpha; o4[jj].z *= alpha; o4[jj].w *= alpha;
        }
        #pragma unroll 4
        for (int kc = 0; kc < 32; ++kc) {
            const float pv = Ss[r][kc];
            const float4* vrow = reinterpret_cast<const float4*>(&Vs[kc][0]);
            #pragma unroll
            for (int jj = 0; jj < 4; ++jj) {
                float4 vv = vrow[gg + 8*jj];
                o4[jj].x = fmaf(pv, vv.x, o4[jj].x);
                o4[jj].y = fmaf(pv, vv.y, o4[jj].y);
                o4[jj].z = fmaf(pv, vv.z, o4[jj].z);
                o4[jj].w = fmaf(pv, vv.w, o4[jj].w);
            }
        }
    }

    const float inv = 1.f / l_run;
    float* obase = o + (size_t)(b*kS + q0 + r) * kDim + h*kHd;
    #pragma unroll
    for (int jj = 0; jj < 4; ++jj) {
        float4 vv;
        vv.x = o4[jj].x * inv; vv.y = o4[jj].y * inv;
        vv.z = o4[jj].z * inv; vv.w = o4[jj].w * inv;
        reinterpret_cast<float4*>(obase)[gg + 8*jj] = vv;
    }
}

// ---------------------------------------------------------------------------
extern "C" void kernel_launch(void* const* d_in, const int* in_sizes, int n_in,
                              void* d_out, int out_size, void* d_ws, size_t ws_size,
                              hipStream_t stream)
{
    (void)in_sizes; (void)n_in; (void)out_size; (void)ws_size;
    const float* x          = (const float*)d_in[0];
    const int*   seq_lens   = (const int*)  d_in[1];
    const int*   grid_sizes = (const int*)  d_in[2];
    const float* freqs      = (const float*)d_in[3];
    const float* Wq = (const float*)d_in[4];
    const float* bq = (const float*)d_in[5];
    const float* Wk = (const float*)d_in[6];
    const float* bk = (const float*)d_in[7];
    const float* Wv = (const float*)d_in[8];
    const float* bv = (const float*)d_in[9];
    const float* Wo = (const float*)d_in[10];
    const float* bo = (const float*)d_in[11];
    const float* gq = (const float*)d_in[12];
    const float* gk = (const float*)d_in[13];
    float* out = (float*)d_out;

    const int M = kB * kS;                 // 6144
    const size_t sz = (size_t)M * kDim;    // 9.44M floats
    float* qb = (float*)d_ws;
    float* kb = qb + sz;
    float* vb = kb + sz;
    float* ab = vb + sz;

    dim3 blk(256);
    dim3 gg(kDim / 128, M / 128);          // (12, 48)
    gemm_bt_kernel<<<gg, blk, 0, stream>>>(x, Wq, bq, qb, M, kDim, kDim);
    gemm_bt_kernel<<<gg, blk, 0, stream>>>(x, Wk, bk, kb, M, kDim, kDim);
    gemm_bt_kernel<<<gg, blk, 0, stream>>>(x, Wv, bv, vb, M, kDim, kDim);
    rmsrope_kernel<<<dim3(M, 2), blk, 0, stream>>>(qb, kb, gq, gk, freqs, grid_sizes);
    attn_kernel<<<dim3(kS/32, kHeads, kB), blk, 0, stream>>>(qb, kb, vb, ab, seq_lens);
    gemm_bt_kernel<<<gg, blk, 0, stream>>>(ab, Wo, bo, out, M, kDim, kDim);
}

// Round 2
// 608.873 us; speedup vs baseline: 7.7851x; 7.7851x over previous
//
#include <hip/hip_runtime.h>
#include <hip/hip_bf16.h>
#include <stdint.h>

typedef __attribute__((ext_vector_type(8))) short short8;
typedef __attribute__((ext_vector_type(4))) float f32x4;

constexpr int kDim   = 1536;
constexpr int kHeads = 12;
constexpr int kHd    = 128;
constexpr int kS     = 3072;
constexpr int kB     = 2;
constexpr float kEps   = 1e-6f;
constexpr float kScale = 0.08838834764831845f; // 1/sqrt(128)

__device__ __forceinline__ ushort f2bf(float f) {
    union { float f; uint32_t u; } c; c.f = f;
    uint32_t u = c.u;
    return (ushort)((u + 0x7fffu + ((u >> 16) & 1u)) >> 16);
}
__device__ __forceinline__ float bf2f(uint32_t h) {
    union { uint32_t u; float f; } c; c.u = h << 16;
    return c.f;
}
__device__ __forceinline__ void gload_lds16(const void* g, void* l) {
    __builtin_amdgcn_global_load_lds((const __attribute__((address_space(1))) void*)g,
                                     (__attribute__((address_space(3))) void*)l, 16, 0, 0);
}

// ---------------------------------------------------------------------------
// fp32 -> bf16 convert, 8 elems/thread
// ---------------------------------------------------------------------------
__global__ __launch_bounds__(256)
void cvt_kernel(const float* __restrict__ in, ushort* __restrict__ out, int n8)
{
    int i = blockIdx.x * 256 + threadIdx.x;
    if (i >= n8) return;
    const float4* p = (const float4*)in + (size_t)i * 2;
    float4 a = p[0], b = p[1];
    uint4 r;
    r.x = (uint32_t)f2bf(a.x) | ((uint32_t)f2bf(a.y) << 16);
    r.y = (uint32_t)f2bf(a.z) | ((uint32_t)f2bf(a.w) << 16);
    r.z = (uint32_t)f2bf(b.x) | ((uint32_t)f2bf(b.y) << 16);
    r.w = (uint32_t)f2bf(b.z) | ((uint32_t)f2bf(b.w) << 16);
    ((uint4*)out)[i] = r;
}

// ---------------------------------------------------------------------------
// bf16 MFMA GEMM: C[M][N] = A[M][K] @ B[N][K]^T + bias   (m97-style 128^2, BK=32)
// ---------------------------------------------------------------------------
template<typename OutT>
__global__ __launch_bounds__(256)
void gemm_bf16(const ushort* __restrict__ A, const ushort* __restrict__ B,
               const float* __restrict__ bias, OutT* __restrict__ C,
               int M, int N, int K)
{
    __shared__ ushort As[128 * 32];
    __shared__ ushort Bs[128 * 32];
    const int t    = threadIdx.x;
    const int lane = t & 63;
    const int w    = t >> 6;
    const int wm = (w >> 1) * 64, wn = (w & 1) * 64;
    const int m0 = blockIdx.y * 128, n0 = blockIdx.x * 128;

    const int srow = t >> 2;           // staging row (0..63), +64 for 2nd call
    const int skc  = (t & 3) * 8;
    const ushort* Ag = A + (size_t)(m0 + srow) * K + skc;
    const ushort* Bg = B + (size_t)(n0 + srow) * K + skc;
    const size_t half = (size_t)64 * K;

    f32x4 acc[4][4];
    #pragma unroll
    for (int m = 0; m < 4; ++m)
        #pragma unroll
        for (int n = 0; n < 4; ++n)
            #pragma unroll
            for (int i = 0; i < 4; ++i) acc[m][n][i] = 0.f;

    const int kk  = (lane >> 4) * 8;
    const int l15 = lane & 15;

    for (int k0 = 0; k0 < K; k0 += 32) {
        __syncthreads();
        gload_lds16(Ag + k0,        &As[t * 8]);
        gload_lds16(Ag + half + k0, &As[t * 8 + 2048]);
        gload_lds16(Bg + k0,        &Bs[t * 8]);
        gload_lds16(Bg + half + k0, &Bs[t * 8 + 2048]);
        __syncthreads();
        short8 af[4], bf[4];
        #pragma unroll
        for (int m = 0; m < 4; ++m) af[m] = *(const short8*)&As[(wm + m*16 + l15) * 32 + kk];
        #pragma unroll
        for (int n = 0; n < 4; ++n) bf[n] = *(const short8*)&Bs[(wn + n*16 + l15) * 32 + kk];
        #pragma unroll
        for (int m = 0; m < 4; ++m)
            #pragma unroll
            for (int n = 0; n < 4; ++n)
                acc[m][n] = __builtin_amdgcn_mfma_f32_16x16x32_bf16(af[m], bf[n], acc[m][n], 0, 0, 0);
    }

    const int r0 = (lane >> 4) * 4;
    #pragma unroll
    for (int m = 0; m < 4; ++m) {
        #pragma unroll
        for (int r = 0; r < 4; ++r) {
            const size_t row = (size_t)(m0 + wm + m*16 + r0 + r);
            #pragma unroll
            for (int n = 0; n < 4; ++n) {
                const int col = n0 + wn + n*16 + l15;
                float val = acc[m][n][r] + bias[col];
                if constexpr (sizeof(OutT) == 4) C[row * N + col] = val;
                else                             C[row * N + col] = f2bf(val);
            }
        }
    }
}

// ---------------------------------------------------------------------------
// RMSNorm (full 1536) + RoPE, bf16 in/out, fp32 math. 192 thr, 8 elems each.
// ---------------------------------------------------------------------------
__global__ __launch_bounds__(192)
void rmsrope_kernel(ushort* __restrict__ qb, ushort* __restrict__ kb,
                    const float* __restrict__ gq, const float* __restrict__ gk,
                    const float* __restrict__ freqs, const int* __restrict__ grid_sizes)
{
    __shared__ float red[4];
    const int row   = blockIdx.x;
    const int which = blockIdx.y;
    ushort* ptr = (which ? kb : qb) + (size_t)row * kDim;
    const float* g = which ? gk : gq;
    const int t = threadIdx.x;

    uint4 raw = ((const uint4*)ptr)[t];
    float v[8];
    v[0] = bf2f(raw.x & 0xffff); v[1] = bf2f(raw.x >> 16);
    v[2] = bf2f(raw.y & 0xffff); v[3] = bf2f(raw.y >> 16);
    v[4] = bf2f(raw.z & 0xffff); v[5] = bf2f(raw.z >> 16);
    v[6] = bf2f(raw.w & 0xffff); v[7] = bf2f(raw.w >> 16);

    float ss = 0.f;
    #pragma unroll
    for (int i = 0; i < 8; ++i) ss += v[i] * v[i];
    #pragma unroll
    for (int off = 32; off >= 1; off >>= 1) ss += __shfl_xor(ss, off);
    if ((t & 63) == 0) red[t >> 6] = ss;
    __syncthreads();
    const float scale = rsqrtf((red[0] + red[1] + red[2]) * (1.f / kDim) + kEps);

    const int b = row / kS, s = row % kS;
    const int gh = grid_sizes[b*3 + 1], gw = grid_sizes[b*3 + 2];
    const int hw  = gh * gw;
    const int fi  = s / hw;
    const int rem = s - fi * hw;
    const int hi  = rem / gw;
    const int wi  = rem - hi * gw;

    const float4 g0 = *(const float4*)(g + t*8);
    const float4 g1 = *(const float4*)(g + t*8 + 4);
    const float gv[8] = {g0.x, g0.y, g0.z, g0.w, g1.x, g1.y, g1.z, g1.w};

    uint32_t out[4];
    #pragma unroll
    for (int jj = 0; jj < 4; ++jj) {
        const int p = t*4 + jj;
        const int c = p & 63;
        const int pos = (c < 22) ? fi : (c < 43 ? hi : wi);
        const float ang = freqs[pos * 64 + c];
        float sn, cs;
        sincosf(ang, &sn, &cs);
        const float e0 = v[2*jj]   * scale * gv[2*jj];
        const float e1 = v[2*jj+1] * scale * gv[2*jj+1];
        const float o0 = e0 * cs - e1 * sn;
        const float o1 = e0 * sn + e1 * cs;
        out[jj] = (uint32_t)f2bf(o0) | ((uint32_t)f2bf(o1) << 16);
    }
    uint4 ov; ov.x = out[0]; ov.y = out[1]; ov.z = out[2]; ov.w = out[3];
    ((uint4*)ptr)[t] = ov;
}

// ---------------------------------------------------------------------------
// Flash attention, bf16 MFMA. 4 waves x 32 q-rows = 128 rows/block, 64-key tiles.
// K staged swizzled (conflict-free B reads); V staged linear -> LDS-transposed.
// ---------------------------------------------------------------------------
__global__ __launch_bounds__(256, 2)
void attn_kernel(const ushort* __restrict__ q, const ushort* __restrict__ k,
                 const ushort* __restrict__ v, ushort* __restrict__ o,
                 const int* __restrict__ seq_lens)
{
    __shared__ ushort Ks[64 * 128];      // swizzled slots
    __shared__ ushort Vs[64 * 128];      // linear staging
    __shared__ ushort Vt[128 * 72];      // transposed [d][key], 16B-aligned rows
    __shared__ ushort Ps[4 * 32 * 72];   // per-wave P

    const int t = threadIdx.x, lane = t & 63, w = t >> 6;
    const int h = blockIdx.y, b = blockIdx.z;
    const int seq = seq_lens[b];
    const int qrow0 = blockIdx.x * 128 + w * 32;
    const ushort* qbase = q + ((size_t)b * kS) * kDim + h * kHd;
    const ushort* kbase = k + ((size_t)b * kS) * kDim + h * kHd;
    const ushort* vbase = v + ((size_t)b * kS) * kDim + h * kHd;

    const int l15 = lane & 15, l4 = lane >> 4;

    // Q fragments in registers (A-operand: row = lane&15, k = (lane>>4)*8+i)
    short8 qf[2][4];
    #pragma unroll
    for (int rb = 0; rb < 2; ++rb)
        #pragma unroll
        for (int kb = 0; kb < 4; ++kb)
            qf[rb][kb] = *(const short8*)(qbase + (size_t)(qrow0 + rb*16 + l15) * kDim + kb*32 + l4*8);

    f32x4 oacc[2][8];
    #pragma unroll
    for (int rb = 0; rb < 2; ++rb)
        #pragma unroll
        for (int nt = 0; nt < 8; ++nt)
            #pragma unroll
            for (int i = 0; i < 4; ++i) oacc[rb][nt][i] = 0.f;
    float mrun[2][4], lrun[2][4];
    #pragma unroll
    for (int rb = 0; rb < 2; ++rb)
        #pragma unroll
        for (int r = 0; r < 4; ++r) { mrun[rb][r] = -1e30f; lrun[rb][r] = 0.f; }

    const int srow = t >> 4;            // 0..15 (+16c)
    const int scol = (t & 15) * 8;
    const int klcol = scol ^ ((srow & 7) << 3);   // pre-swizzled K source column

    for (int kt = 0; kt < kS / 64; ++kt) {
        const int k0 = kt * 64;
        __syncthreads();
        #pragma unroll
        for (int c = 0; c < 4; ++c) {
            const int rr = srow + c * 16;   // rr&7 == srow&7
            gload_lds16(kbase + (size_t)(k0 + rr) * kDim + klcol, &Ks[t*8 + c*2048]);
            gload_lds16(vbase + (size_t)(k0 + rr) * kDim + scol,  &Vs[t*8 + c*2048]);
        }
        __syncthreads();

        // ---- QK^T ----
        f32x4 sacc[2][4];
        #pragma unroll
        for (int rb = 0; rb < 2; ++rb)
            #pragma unroll
            for (int nt = 0; nt < 4; ++nt)
                #pragma unroll
                for (int i = 0; i < 4; ++i) sacc[rb][nt][i] = 0.f;
        #pragma unroll
        for (int kb = 0; kb < 4; ++kb) {
            short8 kf[4];
            #pragma unroll
            for (int nt = 0; nt < 4; ++nt) {
                const int krow = nt * 16 + l15;
                const int kcol = (l4*8 + kb*32) ^ ((krow & 7) << 3);
                kf[nt] = *(const short8*)&Ks[krow * 128 + kcol];
            }
            #pragma unroll
            for (int rb = 0; rb < 2; ++rb)
                #pragma unroll
                for (int nt = 0; nt < 4; ++nt)
                    sacc[rb][nt] = __builtin_amdgcn_mfma_f32_16x16x32_bf16(qf[rb][kb], kf[nt], sacc[rb][nt], 0, 0, 0);
        }

        // ---- V transpose Vs -> Vt ----
        #pragma unroll
        for (int u = 0; u < 4; ++u) {
            const int ui = t + 256 * u;
            const int d = ui & 127, kb8 = ui >> 7;
            short8 tmp;
            #pragma unroll
            for (int j = 0; j < 8; ++j) tmp[j] = (short)Vs[(kb8*8 + j) * 128 + d];
            *(short8*)&Vt[d * 72 + kb8 * 8] = tmp;
        }

        // ---- online softmax ----
        float alpha[2][4];
        #pragma unroll
        for (int rb = 0; rb < 2; ++rb) {
            #pragma unroll
            for (int r = 0; r < 4; ++r) {
                float sc[4];
                #pragma unroll
                for (int nt = 0; nt < 4; ++nt) {
                    float s_ = sacc[rb][nt][r] * kScale;
                    if (k0 + nt*16 + l15 >= seq) s_ = -1e30f;
                    sc[nt] = s_;
                }
                float mx = fmaxf(fmaxf(sc[0], sc[1]), fmaxf(sc[2], sc[3]));
                #pragma unroll
                for (int msk = 1; msk < 16; msk <<= 1) mx = fmaxf(mx, __shfl_xor(mx, msk));
                const float mnew = fmaxf(mrun[rb][r], mx);
                const float a_ = __expf(mrun[rb][r] - mnew);
                mrun[rb][r] = mnew;
                alpha[rb][r] = a_;
                float rs = 0.f;
                #pragma unroll
                for (int nt = 0; nt < 4; ++nt) {
                    const float p = __expf(sc[nt] - mnew);
                    rs += p;
                    Ps[(w*32 + rb*16 + l4*4 + r) * 72 + nt*16 + l15] = f2bf(p);
                }
                #pragma unroll
                for (int msk = 1; msk < 16; msk <<= 1) rs += __shfl_xor(rs, msk);
                lrun[rb][r] = lrun[rb][r] * a_ + rs;
            }
        }
        // rescale O
        #pragma unroll
        for (int rb = 0; rb < 2; ++rb)
            #pragma unroll
            for (int nt = 0; nt < 8; ++nt)
                #pragma unroll
                for (int r = 0; r < 4; ++r)
                    oacc[rb][nt][r] *= alpha[rb][r];
        __syncthreads();

        // ---- PV ----
        #pragma unroll
        for (int kb = 0; kb < 2; ++kb) {
            short8 pf[2];
            #pragma unroll
            for (int rb = 0; rb < 2; ++rb)
                pf[rb] = *(const short8*)&Ps[(w*32 + rb*16 + l15) * 72 + l4*8 + kb*32];
            #pragma unroll
            for (int nt = 0; nt < 8; ++nt) {
                const short8 vf = *(const short8*)&Vt[(nt*16 + l15) * 72 + l4*8 + kb*32];
                #pragma unroll
                for (int rb = 0; rb < 2; ++rb)
                    oacc[rb][nt] = __builtin_amdgcn_mfma_f32_16x16x32_bf16(pf[rb], vf, oacc[rb][nt], 0, 0, 0);
            }
        }
    }

    // epilogue
    #pragma unroll
    for (int rb = 0; rb < 2; ++rb) {
        #pragma unroll
        for (int r = 0; r < 4; ++r) {
            const float inv = 1.f / lrun[rb][r];
            const size_t grow = (size_t)(b * kS + qrow0 + rb*16 + l4*4 + r);
            #pragma unroll
            for (int nt = 0; nt < 8; ++nt)
                o[grow * kDim + h * kHd + nt*16 + l15] = f2bf(oacc[rb][nt][r] * inv);
        }
    }
}

// ---------------------------------------------------------------------------
extern "C" void kernel_launch(void* const* d_in, const int* in_sizes, int n_in,
                              void* d_out, int out_size, void* d_ws, size_t ws_size,
                              hipStream_t stream)
{
    (void)in_sizes; (void)n_in; (void)out_size; (void)ws_size;
    const float* x          = (const float*)d_in[0];
    const int*   seq_lens   = (const int*)  d_in[1];
    const int*   grid_sizes = (const int*)  d_in[2];
    const float* freqs      = (const float*)d_in[3];
    const float* Wq = (const float*)d_in[4];
    const float* bq = (const float*)d_in[5];
    const float* Wk = (const float*)d_in[6];
    const float* bk = (const float*)d_in[7];
    const float* Wv = (const float*)d_in[8];
    const float* bv = (const float*)d_in[9];
    const float* Wo = (const float*)d_in[10];
    const float* bo = (const float*)d_in[11];
    const float* gq = (const float*)d_in[12];
    const float* gk = (const float*)d_in[13];
    float* out = (float*)d_out;

    const int M = kB * kS;                       // 6144
    const size_t szX = (size_t)M * kDim;         // 9,437,184
    const size_t szW = (size_t)kDim * kDim;      // 2,359,296

    ushort* xb  = (ushort*)d_ws;
    ushort* wqb = xb  + szX;
    ushort* wkb = wqb + szW;
    ushort* wvb = wkb + szW;
    ushort* wob = wvb + szW;
    ushort* qb  = wob + szW;
    ushort* kbf = qb  + szX;
    ushort* vbf = kbf + szX;
    ushort* ab  = vbf + szX;

    dim3 blk(256);
    cvt_kernel<<<dim3((int)(szX/8/256)), blk, 0, stream>>>(x,  xb,  (int)(szX/8));
    cvt_kernel<<<dim3((int)(szW/8/256)), blk, 0, stream>>>(Wq, wqb, (int)(szW/8));
    cvt_kernel<<<dim3((int)(szW/8/256)), blk, 0, stream>>>(Wk, wkb, (int)(szW/8));
    cvt_kernel<<<dim3((int)(szW/8/256)), blk, 0, stream>>>(Wv, wvb, (int)(szW/8));
    cvt_kernel<<<dim3((int)(szW/8/256)), blk, 0, stream>>>(Wo, wob, (int)(szW/8));

    dim3 gg(kDim / 128, M / 128);                // (12, 48)
    gemm_bf16<ushort><<<gg, blk, 0, stream>>>(xb, wqb, bq, qb,  M, kDim, kDim);
    gemm_bf16<ushort><<<gg, blk, 0, stream>>>(xb, wkb, bk, kbf, M, kDim, kDim);
    gemm_bf16<ushort><<<gg, blk, 0, stream>>>(xb, wvb, bv, vbf, M, kDim, kDim);

    rmsrope_kernel<<<dim3(M, 2), dim3(192), 0, stream>>>(qb, kbf, gq, gk, freqs, grid_sizes);

    attn_kernel<<<dim3(kS/128, kHeads, kB), blk, 0, stream>>>(qb, kbf, vbf, ab, seq_lens);

    gemm_bf16<float><<<gg, blk, 0, stream>>>(ab, wob, bo, out, M, kDim, kDim);
}

// Round 3
// 591.357 us; speedup vs baseline: 8.0157x; 1.0296x over previous
//
#include <hip/hip_runtime.h>
#include <hip/hip_bf16.h>
#include <stdint.h>

typedef __attribute__((ext_vector_type(8))) short short8;
typedef __attribute__((ext_vector_type(4))) float f32x4;
typedef __attribute__((ext_vector_type(16))) float f32x16;

constexpr int kDim   = 1536;
constexpr int kHeads = 12;
constexpr int kHd    = 128;
constexpr int kS     = 3072;
constexpr int kB     = 2;
constexpr float kEps   = 1e-6f;
constexpr float kScale = 0.08838834764831845f; // 1/sqrt(128)

__device__ __forceinline__ ushort f2bf(float f) {
    union { float f; uint32_t u; } c; c.f = f;
    uint32_t u = c.u;
    return (ushort)((u + 0x7fffu + ((u >> 16) & 1u)) >> 16);
}
__device__ __forceinline__ float bf2f(uint32_t h) {
    union { uint32_t u; float f; } c; c.u = h << 16;
    return c.f;
}
__device__ __forceinline__ void gload_lds16(const void* g, void* l) {
    __builtin_amdgcn_global_load_lds((const __attribute__((address_space(1))) void*)g,
                                     (__attribute__((address_space(3))) void*)l, 16, 0, 0);
}

// ---------------------------------------------------------------------------
// fp32 -> bf16 convert, 8 elems/thread
// ---------------------------------------------------------------------------
__global__ __launch_bounds__(256)
void cvt_kernel(const float* __restrict__ in, ushort* __restrict__ out, int n8)
{
    int i = blockIdx.x * 256 + threadIdx.x;
    if (i >= n8) return;
    const float4* p = (const float4*)in + (size_t)i * 2;
    float4 a = p[0], b = p[1];
    uint4 r;
    r.x = (uint32_t)f2bf(a.x) | ((uint32_t)f2bf(a.y) << 16);
    r.y = (uint32_t)f2bf(a.z) | ((uint32_t)f2bf(a.w) << 16);
    r.z = (uint32_t)f2bf(b.x) | ((uint32_t)f2bf(b.y) << 16);
    r.w = (uint32_t)f2bf(b.z) | ((uint32_t)f2bf(b.w) << 16);
    ((uint4*)out)[i] = r;
}

// ---------------------------------------------------------------------------
// bf16 MFMA GEMM: C[M][N] = A[M][K] @ B[N][K]^T + bias   (m97-style 128^2, BK=32)
// ---------------------------------------------------------------------------
template<typename OutT>
__global__ __launch_bounds__(256)
void gemm_bf16(const ushort* __restrict__ A, const ushort* __restrict__ B,
               const float* __restrict__ bias, OutT* __restrict__ C,
               int M, int N, int K)
{
    __shared__ ushort As[128 * 32];
    __shared__ ushort Bs[128 * 32];
    const int t    = threadIdx.x;
    const int lane = t & 63;
    const int w    = t >> 6;
    const int wm = (w >> 1) * 64, wn = (w & 1) * 64;
    const int m0 = blockIdx.y * 128, n0 = blockIdx.x * 128;

    const int srow = t >> 2;
    const int skc  = (t & 3) * 8;
    const ushort* Ag = A + (size_t)(m0 + srow) * K + skc;
    const ushort* Bg = B + (size_t)(n0 + srow) * K + skc;
    const size_t half = (size_t)64 * K;

    f32x4 acc[4][4];
    #pragma unroll
    for (int m = 0; m < 4; ++m)
        #pragma unroll
        for (int n = 0; n < 4; ++n)
            #pragma unroll
            for (int i = 0; i < 4; ++i) acc[m][n][i] = 0.f;

    const int kk  = (lane >> 4) * 8;
    const int l15 = lane & 15;

    for (int k0 = 0; k0 < K; k0 += 32) {
        __syncthreads();
        gload_lds16(Ag + k0,        &As[t * 8]);
        gload_lds16(Ag + half + k0, &As[t * 8 + 2048]);
        gload_lds16(Bg + k0,        &Bs[t * 8]);
        gload_lds16(Bg + half + k0, &Bs[t * 8 + 2048]);
        __syncthreads();
        short8 af[4], bf[4];
        #pragma unroll
        for (int m = 0; m < 4; ++m) af[m] = *(const short8*)&As[(wm + m*16 + l15) * 32 + kk];
        #pragma unroll
        for (int n = 0; n < 4; ++n) bf[n] = *(const short8*)&Bs[(wn + n*16 + l15) * 32 + kk];
        #pragma unroll
        for (int m = 0; m < 4; ++m)
            #pragma unroll
            for (int n = 0; n < 4; ++n)
                acc[m][n] = __builtin_amdgcn_mfma_f32_16x16x32_bf16(af[m], bf[n], acc[m][n], 0, 0, 0);
    }

    const int r0 = (lane >> 4) * 4;
    #pragma unroll
    for (int m = 0; m < 4; ++m) {
        #pragma unroll
        for (int r = 0; r < 4; ++r) {
            const size_t row = (size_t)(m0 + wm + m*16 + r0 + r);
            #pragma unroll
            for (int n = 0; n < 4; ++n) {
                const int col = n0 + wn + n*16 + l15;
                float val = acc[m][n][r] + bias[col];
                if constexpr (sizeof(OutT) == 4) C[row * N + col] = val;
                else                             C[row * N + col] = f2bf(val);
            }
        }
    }
}

// ---------------------------------------------------------------------------
// RMSNorm (full 1536) + RoPE, bf16 in/out, fp32 math. 192 thr, 8 elems each.
// ---------------------------------------------------------------------------
__global__ __launch_bounds__(192)
void rmsrope_kernel(ushort* __restrict__ qb, ushort* __restrict__ kb,
                    const float* __restrict__ gq, const float* __restrict__ gk,
                    const float* __restrict__ freqs, const int* __restrict__ grid_sizes)
{
    __shared__ float red[4];
    const int row   = blockIdx.x;
    const int which = blockIdx.y;
    ushort* ptr = (which ? kb : qb) + (size_t)row * kDim;
    const float* g = which ? gk : gq;
    const int t = threadIdx.x;

    uint4 raw = ((const uint4*)ptr)[t];
    float v[8];
    v[0] = bf2f(raw.x & 0xffff); v[1] = bf2f(raw.x >> 16);
    v[2] = bf2f(raw.y & 0xffff); v[3] = bf2f(raw.y >> 16);
    v[4] = bf2f(raw.z & 0xffff); v[5] = bf2f(raw.z >> 16);
    v[6] = bf2f(raw.w & 0xffff); v[7] = bf2f(raw.w >> 16);

    float ss = 0.f;
    #pragma unroll
    for (int i = 0; i < 8; ++i) ss += v[i] * v[i];
    #pragma unroll
    for (int off = 32; off >= 1; off >>= 1) ss += __shfl_xor(ss, off);
    if ((t & 63) == 0) red[t >> 6] = ss;
    __syncthreads();
    const float scale = rsqrtf((red[0] + red[1] + red[2]) * (1.f / kDim) + kEps);

    const int b = row / kS, s = row % kS;
    const int gh = grid_sizes[b*3 + 1], gw = grid_sizes[b*3 + 2];
    const int hw  = gh * gw;
    const int fi  = s / hw;
    const int rem = s - fi * hw;
    const int hi  = rem / gw;
    const int wi  = rem - hi * gw;

    const float4 g0 = *(const float4*)(g + t*8);
    const float4 g1 = *(const float4*)(g + t*8 + 4);
    const float gv[8] = {g0.x, g0.y, g0.z, g0.w, g1.x, g1.y, g1.z, g1.w};

    uint32_t out[4];
    #pragma unroll
    for (int jj = 0; jj < 4; ++jj) {
        const int p = t*4 + jj;
        const int c = p & 63;
        const int pos = (c < 22) ? fi : (c < 43 ? hi : wi);
        const float ang = freqs[pos * 64 + c];
        float sn, cs;
        sincosf(ang, &sn, &cs);
        const float e0 = v[2*jj]   * scale * gv[2*jj];
        const float e1 = v[2*jj+1] * scale * gv[2*jj+1];
        const float o0 = e0 * cs - e1 * sn;
        const float o1 = e0 * sn + e1 * cs;
        out[jj] = (uint32_t)f2bf(o0) | ((uint32_t)f2bf(o1) << 16);
    }
    uint4 ov; ov.x = out[0]; ov.y = out[1]; ov.z = out[2]; ov.w = out[3];
    ((uint4*)ptr)[t] = ov;
}

// ---------------------------------------------------------------------------
// Flash attention, swapped-QK^T 32x32x16 MFMA. 4 waves x 32 q-rows = 128/block.
// Lane owns q-row (col of S^T); softmax fully in-register; P->PV via
// bf16 pack + hi/lo half exchange (shfl_xor 32). KVBLK=64.
// K: global_load_lds with pre-swizzled source cols (XOR (row&7)<<3).
// V: reg-staged transposed into VT[128][64], col ^= (d&7)<<3, rotated writes.
// ---------------------------------------------------------------------------
__global__ __launch_bounds__(256, 2)
void attn_kernel(const ushort* __restrict__ q, const ushort* __restrict__ k,
                 const ushort* __restrict__ v, ushort* __restrict__ o,
                 const int* __restrict__ seq_lens)
{
    __shared__ ushort Ks[64 * 128];
    __shared__ ushort VT[128 * 64];

    const int t = threadIdx.x, lane = t & 63, w = t >> 6;
    const int h = blockIdx.y, b = blockIdx.z;
    const int seq = seq_lens[b];
    const int l31 = lane & 31, hi = lane >> 5;
    const int qrow = blockIdx.x * 128 + w * 32 + l31;

    const ushort* qbase = q + ((size_t)b * kS) * kDim + h * kHd;
    const ushort* kbase = k + ((size_t)b * kS) * kDim + h * kHd;
    const ushort* vbase = v + ((size_t)b * kS) * kDim + h * kHd;

    // Q fragments (B-operand): qf[kb][j] = Q[qrow][kb*16 + hi*8 + j]
    short8 qf[8];
    #pragma unroll
    for (int kb = 0; kb < 8; ++kb)
        qf[kb] = *(const short8*)(qbase + (size_t)qrow * kDim + kb*16 + hi*8);

    f32x16 oacc[4];
    #pragma unroll
    for (int n = 0; n < 4; ++n)
        #pragma unroll
        for (int i = 0; i < 16; ++i) oacc[n][i] = 0.f;

    float m_run = -1e30f, l_run = 0.f;

    const int srow = t >> 4;            // 0..15
    const int scol = (t & 15) * 8;
    const int kl   = scol ^ ((srow & 7) << 3);   // pre-swizzled K source col
    const int vkey0 = t >> 4;
    const int vc    = t & 15;

    const float sc = kScale * 1.44269504089f;    // fold log2(e): exp2 domain

    for (int k0 = 0; k0 < kS; k0 += 64) {
        __syncthreads();
        // ---- stage K (swizzled source -> linear LDS) ----
        #pragma unroll
        for (int c = 0; c < 4; ++c)
            gload_lds16(kbase + (size_t)(k0 + srow + c*16) * kDim + kl, &Ks[t*8 + c*2048]);
        // ---- stage V transposed: VT[d][key ^ ((d&7)<<3)] ----
        #pragma unroll
        for (int g = 0; g < 4; ++g) {
            const int key = vkey0 + g * 16;
            short8 vv = *(const short8*)(vbase + (size_t)(k0 + key) * kDim + vc * 8);
            #pragma unroll
            for (int s = 0; s < 8; ++s) {
                const int e = (s + vc) & 7;     // rotate write order: bank-spread
                VT[(vc*8 + e) * 64 + (key ^ (e << 3))] = (ushort)vv[e];
            }
        }
        __syncthreads();

        // ---- S^T = K · Q^T : col(lane&31)=qrow, reg r -> key (r&3)+8*(r>>2)+4*hi
        f32x16 s0, s1;
        #pragma unroll
        for (int i = 0; i < 16; ++i) { s0[i] = 0.f; s1[i] = 0.f; }
        #pragma unroll
        for (int kb = 0; kb < 8; ++kb) {
            const int col = (kb*16 + hi*8) ^ ((l31 & 7) << 3);
            short8 kf0 = *(const short8*)&Ks[l31 * 128 + col];
            short8 kf1 = *(const short8*)&Ks[(32 + l31) * 128 + col];
            s0 = __builtin_amdgcn_mfma_f32_32x32x16_bf16(kf0, qf[kb], s0, 0, 0, 0);
            s1 = __builtin_amdgcn_mfma_f32_32x32x16_bf16(kf1, qf[kb], s1, 0, 0, 0);
        }

        // ---- scale to base-2, mask, tile max ----
        float mx = -1e30f;
        #pragma unroll
        for (int r = 0; r < 16; ++r) {
            float f0 = s0[r] * sc;
            float f1 = s1[r] * sc;
            if (k0 + 64 > seq) {
                const int key = k0 + (r&3) + 8*(r>>2) + 4*hi;
                if (key >= seq)      f0 = -1e30f;
                if (key + 32 >= seq) f1 = -1e30f;
            }
            s0[r] = f0; s1[r] = f1;
            mx = fmaxf(fmaxf(mx, f0), f1);
        }
        mx = fmaxf(mx, __shfl_xor(mx, 32));

        // ---- defer-max online softmax (T13) ----
        const bool skip = (mx <= m_run + 11.0f);
        if (!__all(skip)) {
            const float mnew = fmaxf(m_run, mx);
            const float alpha = exp2f(m_run - mnew);
            m_run = mnew;
            l_run *= alpha;
            #pragma unroll
            for (int r = 0; r < 16; ++r) {
                const float ar = __shfl(alpha, (r&3) + 8*(r>>2) + 4*hi);
                #pragma unroll
                for (int n = 0; n < 4; ++n) oacc[n][r] *= ar;
            }
        }

        float rs = 0.f;
        #pragma unroll
        for (int r = 0; r < 16; ++r) {
            s0[r] = exp2f(s0[r] - m_run);
            s1[r] = exp2f(s1[r] - m_run);
            rs += s0[r] + s1[r];
        }
        rs += __shfl_xor(rs, 32);
        l_run += rs;

        // ---- pack P -> bf16 dwords, exchange halves, assemble A-frags ----
        uint32_t u0[8], u1[8], w0[8], w1[8];
        #pragma unroll
        for (int i = 0; i < 8; ++i) {
            u0[i] = (uint32_t)f2bf(s0[2*i]) | ((uint32_t)f2bf(s0[2*i+1]) << 16);
            u1[i] = (uint32_t)f2bf(s1[2*i]) | ((uint32_t)f2bf(s1[2*i+1]) << 16);
        }
        #pragma unroll
        for (int i = 0; i < 8; ++i) {
            w0[i] = __shfl_xor(u0[i], 32);
            w1[i] = __shfl_xor(u1[i], 32);
        }
        union PF { uint32_t d[4]; short8 s8; };
        PF pa[4];
        pa[0].d[0] = hi ? w0[2] : u0[0];  pa[0].d[1] = hi ? w0[3] : u0[1];
        pa[0].d[2] = hi ? u0[2] : w0[0];  pa[0].d[3] = hi ? u0[3] : w0[1];
        pa[1].d[0] = hi ? w0[6] : u0[4];  pa[1].d[1] = hi ? w0[7] : u0[5];
        pa[1].d[2] = hi ? u0[6] : w0[4];  pa[1].d[3] = hi ? u0[7] : w0[5];
        pa[2].d[0] = hi ? w1[2] : u1[0];  pa[2].d[1] = hi ? w1[3] : u1[1];
        pa[2].d[2] = hi ? u1[2] : w1[0];  pa[2].d[3] = hi ? u1[3] : w1[1];
        pa[3].d[0] = hi ? w1[6] : u1[4];  pa[3].d[1] = hi ? w1[7] : u1[5];
        pa[3].d[2] = hi ? u1[6] : w1[4];  pa[3].d[3] = hi ? u1[7] : w1[5];

        // ---- PV: oacc[n] over d-blocks, k-slots 0..3 ----
        #pragma unroll
        for (int ks = 0; ks < 4; ++ks) {
            #pragma unroll
            for (int n = 0; n < 4; ++n) {
                const int d = n*32 + l31;
                const int colv = (ks*16 + hi*8) ^ ((l31 & 7) << 3);
                short8 vf = *(const short8*)&VT[d * 64 + colv];
                oacc[n] = __builtin_amdgcn_mfma_f32_32x32x16_bf16(pa[ks].s8, vf, oacc[n], 0, 0, 0);
            }
        }
    }

    // ---- epilogue: O[qrow(reg)][d(col)] / l ----
    const float linv = 1.f / l_run;
    #pragma unroll
    for (int r = 0; r < 16; ++r) {
        const int qr = (r&3) + 8*(r>>2) + 4*hi;
        const float lr = __shfl(linv, qr);
        const size_t row = (size_t)(b * kS) + blockIdx.x * 128 + w * 32 + qr;
        #pragma unroll
        for (int n = 0; n < 4; ++n)
            o[row * kDim + h * kHd + n*32 + l31] = f2bf(oacc[n][r] * lr);
    }
}

// ---------------------------------------------------------------------------
extern "C" void kernel_launch(void* const* d_in, const int* in_sizes, int n_in,
                              void* d_out, int out_size, void* d_ws, size_t ws_size,
                              hipStream_t stream)
{
    (void)in_sizes; (void)n_in; (void)out_size; (void)ws_size;
    const float* x          = (const float*)d_in[0];
    const int*   seq_lens   = (const int*)  d_in[1];
    const int*   grid_sizes = (const int*)  d_in[2];
    const float* freqs      = (const float*)d_in[3];
    const float* Wq = (const float*)d_in[4];
    const float* bq = (const float*)d_in[5];
    const float* Wk = (const float*)d_in[6];
    const float* bk = (const float*)d_in[7];
    const float* Wv = (const float*)d_in[8];
    const float* bv = (const float*)d_in[9];
    const float* Wo = (const float*)d_in[10];
    const float* bo = (const float*)d_in[11];
    const float* gq = (const float*)d_in[12];
    const float* gk = (const float*)d_in[13];
    float* out = (float*)d_out;

    const int M = kB * kS;                       // 6144
    const size_t szX = (size_t)M * kDim;
    const size_t szW = (size_t)kDim * kDim;

    ushort* xb  = (ushort*)d_ws;
    ushort* wqb = xb  + szX;
    ushort* wkb = wqb + szW;
    ushort* wvb = wkb + szW;
    ushort* wob = wvb + szW;
    ushort* qb  = wob + szW;
    ushort* kbf = qb  + szX;
    ushort* vbf = kbf + szX;
    ushort* ab  = vbf + szX;

    dim3 blk(256);
    cvt_kernel<<<dim3((int)(szX/8/256)), blk, 0, stream>>>(x,  xb,  (int)(szX/8));
    cvt_kernel<<<dim3((int)(szW/8/256)), blk, 0, stream>>>(Wq, wqb, (int)(szW/8));
    cvt_kernel<<<dim3((int)(szW/8/256)), blk, 0, stream>>>(Wk, wkb, (int)(szW/8));
    cvt_kernel<<<dim3((int)(szW/8/256)), blk, 0, stream>>>(Wv, wvb, (int)(szW/8));
    cvt_kernel<<<dim3((int)(szW/8/256)), blk, 0, stream>>>(Wo, wob, (int)(szW/8));

    dim3 gg(kDim / 128, M / 128);                // (12, 48)
    gemm_bf16<ushort><<<gg, blk, 0, stream>>>(xb, wqb, bq, qb,  M, kDim, kDim);
    gemm_bf16<ushort><<<gg, blk, 0, stream>>>(xb, wkb, bk, kbf, M, kDim, kDim);
    gemm_bf16<ushort><<<gg, blk, 0, stream>>>(xb, wvb, bv, vbf, M, kDim, kDim);

    rmsrope_kernel<<<dim3(M, 2), dim3(192), 0, stream>>>(qb, kbf, gq, gk, freqs, grid_sizes);

    attn_kernel<<<dim3(kS/128, kHeads, kB), blk, 0, stream>>>(qb, kbf, vbf, ab, seq_lens);

    gemm_bf16<float><<<gg, blk, 0, stream>>>(ab, wob, bo, out, M, kDim, kDim);
}

// Round 5
// 502.226 us; speedup vs baseline: 9.4383x; 1.1775x over previous
//
#include <hip/hip_runtime.h>
#include <hip/hip_bf16.h>
#include <stdint.h>

typedef __attribute__((ext_vector_type(8))) short short8;
typedef __attribute__((ext_vector_type(4))) float f32x4;
typedef __attribute__((ext_vector_type(16))) float f32x16;

constexpr int kDim   = 1536;
constexpr int kHeads = 12;
constexpr int kHd    = 128;
constexpr int kS     = 3072;
constexpr int kB     = 2;
constexpr float kEps   = 1e-6f;
constexpr float kQMul  = 0.08838834764831845f * 1.44269504089f; // 1/sqrt(128) * log2(e)

__device__ __forceinline__ ushort f2bf(float f) {
    union { float f; uint32_t u; } c; c.f = f;
    uint32_t u = c.u;
    return (ushort)((u + 0x7fffu + ((u >> 16) & 1u)) >> 16);
}
__device__ __forceinline__ float bf2f(uint32_t h) {
    union { uint32_t u; float f; } c; c.u = h << 16;
    return c.f;
}
__device__ __forceinline__ void gload_lds16(const void* g, void* l) {
    __builtin_amdgcn_global_load_lds((const __attribute__((address_space(1))) void*)g,
                                     (__attribute__((address_space(3))) void*)l, 16, 0, 0);
}
__device__ __forceinline__ uint32_t cvtpk_bf16(float lo, float hi) {
    uint32_t r;
    asm("v_cvt_pk_bf16_f32 %0, %1, %2" : "=v"(r) : "v"(lo), "v"(hi));
    return r;
}

// ---------------------------------------------------------------------------
// fp32 -> bf16 convert, 8 elems/thread
// ---------------------------------------------------------------------------
__global__ __launch_bounds__(256)
void cvt_kernel(const float* __restrict__ in, ushort* __restrict__ out, int n8)
{
    int i = blockIdx.x * 256 + threadIdx.x;
    if (i >= n8) return;
    const float4* p = (const float4*)in + (size_t)i * 2;
    float4 a = p[0], b = p[1];
    uint4 r;
    r.x = (uint32_t)f2bf(a.x) | ((uint32_t)f2bf(a.y) << 16);
    r.y = (uint32_t)f2bf(a.z) | ((uint32_t)f2bf(a.w) << 16);
    r.z = (uint32_t)f2bf(b.x) | ((uint32_t)f2bf(b.y) << 16);
    r.w = (uint32_t)f2bf(b.z) | ((uint32_t)f2bf(b.w) << 16);
    ((uint4*)out)[i] = r;
}

// ---------------------------------------------------------------------------
// bf16 MFMA GEMM: C[M][N] = A[M][K] @ B[N][K]^T + bias   (m97-style 128^2, BK=32)
// ---------------------------------------------------------------------------
template<typename OutT>
__global__ __launch_bounds__(256)
void gemm_bf16(const ushort* __restrict__ A, const ushort* __restrict__ B,
               const float* __restrict__ bias, OutT* __restrict__ C,
               int M, int N, int K)
{
    __shared__ ushort As[128 * 32];
    __shared__ ushort Bs[128 * 32];
    const int t    = threadIdx.x;
    const int lane = t & 63;
    const int w    = t >> 6;
    const int wm = (w >> 1) * 64, wn = (w & 1) * 64;
    const int m0 = blockIdx.y * 128, n0 = blockIdx.x * 128;

    const int srow = t >> 2;
    const int skc  = (t & 3) * 8;
    const ushort* Ag = A + (size_t)(m0 + srow) * K + skc;
    const ushort* Bg = B + (size_t)(n0 + srow) * K + skc;
    const size_t half = (size_t)64 * K;

    f32x4 acc[4][4];
    #pragma unroll
    for (int m = 0; m < 4; ++m)
        #pragma unroll
        for (int n = 0; n < 4; ++n)
            #pragma unroll
            for (int i = 0; i < 4; ++i) acc[m][n][i] = 0.f;

    const int kk  = (lane >> 4) * 8;
    const int l15 = lane & 15;

    for (int k0 = 0; k0 < K; k0 += 32) {
        __syncthreads();
        gload_lds16(Ag + k0,        &As[t * 8]);
        gload_lds16(Ag + half + k0, &As[t * 8 + 2048]);
        gload_lds16(Bg + k0,        &Bs[t * 8]);
        gload_lds16(Bg + half + k0, &Bs[t * 8 + 2048]);
        __syncthreads();
        short8 af[4], bf[4];
        #pragma unroll
        for (int m = 0; m < 4; ++m) af[m] = *(const short8*)&As[(wm + m*16 + l15) * 32 + kk];
        #pragma unroll
        for (int n = 0; n < 4; ++n) bf[n] = *(const short8*)&Bs[(wn + n*16 + l15) * 32 + kk];
        #pragma unroll
        for (int m = 0; m < 4; ++m)
            #pragma unroll
            for (int n = 0; n < 4; ++n)
                acc[m][n] = __builtin_amdgcn_mfma_f32_16x16x32_bf16(af[m], bf[n], acc[m][n], 0, 0, 0);
    }

    const int r0 = (lane >> 4) * 4;
    #pragma unroll
    for (int m = 0; m < 4; ++m) {
        #pragma unroll
        for (int r = 0; r < 4; ++r) {
            const size_t row = (size_t)(m0 + wm + m*16 + r0 + r);
            #pragma unroll
            for (int n = 0; n < 4; ++n) {
                const int col = n0 + wn + n*16 + l15;
                float val = acc[m][n][r] + bias[col];
                if constexpr (sizeof(OutT) == 4) C[row * N + col] = val;
                else                             C[row * N + col] = f2bf(val);
            }
        }
    }
}

// ---------------------------------------------------------------------------
// V transpose: vt[b][h][d][s] = v[b][s][h*128+d].  64x64 tiles via LDS.
// ---------------------------------------------------------------------------
__global__ __launch_bounds__(256)
void vtrans_kernel(const ushort* __restrict__ v, ushort* __restrict__ vt)
{
    __shared__ ushort Ts[64][72];
    const int t  = threadIdx.x;
    const int s0 = blockIdx.x * 64;
    const int d0 = blockIdx.y * 64;
    const int bh = blockIdx.z;
    const int b = bh / kHeads, h = bh % kHeads;

    const int r = t >> 2, cc = (t & 3) * 16;
    const ushort* src = v + ((size_t)(b * kS) + s0 + r) * kDim + h * kHd + d0 + cc;
    uint4 a0 = *(const uint4*)src;
    uint4 a1 = *(const uint4*)(src + 8);
    *(uint4*)&Ts[r][cc]     = a0;
    *(uint4*)&Ts[r][cc + 8] = a1;
    __syncthreads();
    ushort tmp[16];
    #pragma unroll
    for (int j = 0; j < 16; ++j) tmp[j] = Ts[cc + j][r];
    ushort* dst = vt + ((size_t)(bh * kHd) + d0 + r) * kS + s0 + cc;
    *(uint4*)dst       = *(uint4*)&tmp[0];
    *(uint4*)(dst + 8) = *(uint4*)&tmp[8];
}

// ---------------------------------------------------------------------------
// RMSNorm (full 1536) + RoPE, bf16 in/out, fp32 math. 192 thr, 8 elems each.
// Q additionally scaled by 1/sqrt(d)*log2(e) (folded attention scale).
// ---------------------------------------------------------------------------
__global__ __launch_bounds__(192)
void rmsrope_kernel(ushort* __restrict__ qb, ushort* __restrict__ kb,
                    const float* __restrict__ gq, const float* __restrict__ gk,
                    const float* __restrict__ freqs, const int* __restrict__ grid_sizes)
{
    __shared__ float red[4];
    const int row   = blockIdx.x;
    const int which = blockIdx.y;
    ushort* ptr = (which ? kb : qb) + (size_t)row * kDim;
    const float* g = which ? gk : gq;
    const float outmul = which ? 1.0f : kQMul;
    const int t = threadIdx.x;

    uint4 raw = ((const uint4*)ptr)[t];
    float v[8];
    v[0] = bf2f(raw.x & 0xffff); v[1] = bf2f(raw.x >> 16);
    v[2] = bf2f(raw.y & 0xffff); v[3] = bf2f(raw.y >> 16);
    v[4] = bf2f(raw.z & 0xffff); v[5] = bf2f(raw.z >> 16);
    v[6] = bf2f(raw.w & 0xffff); v[7] = bf2f(raw.w >> 16);

    float ss = 0.f;
    #pragma unroll
    for (int i = 0; i < 8; ++i) ss += v[i] * v[i];
    #pragma unroll
    for (int off = 32; off >= 1; off >>= 1) ss += __shfl_xor(ss, off);
    if ((t & 63) == 0) red[t >> 6] = ss;
    __syncthreads();
    const float scale = rsqrtf((red[0] + red[1] + red[2]) * (1.f / kDim) + kEps);

    const int b = row / kS, s = row % kS;
    const int gh = grid_sizes[b*3 + 1], gw = grid_sizes[b*3 + 2];
    const int hw  = gh * gw;
    const int fi  = s / hw;
    const int rem = s - fi * hw;
    const int hi  = rem / gw;
    const int wi  = rem - hi * gw;

    const float4 g0 = *(const float4*)(g + t*8);
    const float4 g1 = *(const float4*)(g + t*8 + 4);
    const float gv[8] = {g0.x, g0.y, g0.z, g0.w, g1.x, g1.y, g1.z, g1.w};

    uint32_t out[4];
    #pragma unroll
    for (int jj = 0; jj < 4; ++jj) {
        const int p = t*4 + jj;
        const int c = p & 63;
        const int pos = (c < 22) ? fi : (c < 43 ? hi : wi);
        const float ang = freqs[pos * 64 + c];
        float sn, cs;
        sincosf(ang, &sn, &cs);
        const float e0 = v[2*jj]   * scale * gv[2*jj];
        const float e1 = v[2*jj+1] * scale * gv[2*jj+1];
        const float o0 = (e0 * cs - e1 * sn) * outmul;
        const float o1 = (e0 * sn + e1 * cs) * outmul;
        out[jj] = (uint32_t)f2bf(o0) | ((uint32_t)f2bf(o1) << 16);
    }
    uint4 ov; ov.x = out[0]; ov.y = out[1]; ov.z = out[2]; ov.w = out[3];
    ((uint4*)ptr)[t] = ov;
}

// ---------------------------------------------------------------------------
// Flash attention, swapped-QK^T 32x32x16 MFMA. 4 waves x 32 q-rows = 128/block.
// K and V^T both staged via global_load_lds with pre-swizzled source columns.
// Softmax in-register; P pack via v_cvt_pk_bf16_f32; half-exchange via
// __shfl_xor(.,32) + hi/lo select (r3-verified). Q pre-scaled (kQMul).
// ---------------------------------------------------------------------------
__global__ __launch_bounds__(256, 2)
void attn_kernel(const ushort* __restrict__ q, const ushort* __restrict__ k,
                 const ushort* __restrict__ vt, ushort* __restrict__ o,
                 const int* __restrict__ seq_lens)
{
    __shared__ ushort Ks[64 * 128];
    __shared__ ushort VT[128 * 64];

    const int t = threadIdx.x, lane = t & 63, w = t >> 6;
    const int h = blockIdx.y, b = blockIdx.z;
    const int seq = seq_lens[b];
    const int l31 = lane & 31, hi = lane >> 5;
    const int qrow = blockIdx.x * 128 + w * 32 + l31;

    const ushort* qbase = q + ((size_t)b * kS) * kDim + h * kHd;
    const ushort* kbase = k + ((size_t)b * kS) * kDim + h * kHd;
    const ushort* vtbase = vt + ((size_t)(b * kHeads + h) * kHd) * kS;

    // Q fragments (B-operand): qf[kb][j] = Q[qrow][kb*16 + hi*8 + j]
    short8 qf[8];
    #pragma unroll
    for (int kb = 0; kb < 8; ++kb)
        qf[kb] = *(const short8*)(qbase + (size_t)qrow * kDim + kb*16 + hi*8);

    f32x16 oacc[4];
    #pragma unroll
    for (int n = 0; n < 4; ++n)
        #pragma unroll
        for (int i = 0; i < 16; ++i) oacc[n][i] = 0.f;

    float m_run = -1e30f, l_run = 0.f;

    const int srow = t >> 4;                      // 0..15
    const int scol = (t & 15) * 8;
    const int kl   = scol ^ ((srow & 7) << 3);    // pre-swizzled K source col
    const int vd0  = t >> 3;                      // 0..31
    const int vscol = ((t & 7) * 8) ^ ((vd0 & 7) << 3);  // pre-swizzled V^T col

    for (int k0 = 0; k0 < kS; k0 += 64) {
        __syncthreads();
        #pragma unroll
        for (int c = 0; c < 4; ++c) {
            gload_lds16(kbase + (size_t)(k0 + srow + c*16) * kDim + kl, &Ks[t*8 + c*2048]);
            gload_lds16(vtbase + (size_t)(vd0 + c*32) * kS + k0 + vscol, &VT[t*8 + c*2048]);
        }
        __syncthreads();

        // ---- S^T = K . Q^T : col(lane&31)=qrow, reg r -> key (r&3)+8*(r>>2)+4*hi
        f32x16 s0, s1;
        #pragma unroll
        for (int i = 0; i < 16; ++i) { s0[i] = 0.f; s1[i] = 0.f; }
        __builtin_amdgcn_s_setprio(1);
        #pragma unroll
        for (int kb = 0; kb < 8; ++kb) {
            const int col = (kb*16 + hi*8) ^ ((l31 & 7) << 3);
            short8 kf0 = *(const short8*)&Ks[l31 * 128 + col];
            short8 kf1 = *(const short8*)&Ks[(32 + l31) * 128 + col];
            s0 = __builtin_amdgcn_mfma_f32_32x32x16_bf16(kf0, qf[kb], s0, 0, 0, 0);
            s1 = __builtin_amdgcn_mfma_f32_32x32x16_bf16(kf1, qf[kb], s1, 0, 0, 0);
        }
        __builtin_amdgcn_s_setprio(0);

        // ---- mask + tile max (scores already in log2 domain via kQMul) ----
        float mx = -1e30f;
        if (k0 + 64 > seq) {
            #pragma unroll
            for (int r = 0; r < 16; ++r) {
                const int key = k0 + (r&3) + 8*(r>>2) + 4*hi;
                if (key >= seq)      s0[r] = -1e30f;
                if (key + 32 >= seq) s1[r] = -1e30f;
                mx = fmaxf(fmaxf(mx, s0[r]), s1[r]);
            }
        } else {
            #pragma unroll
            for (int r = 0; r < 16; ++r) mx = fmaxf(fmaxf(mx, s0[r]), s1[r]);
        }
        mx = fmaxf(mx, __shfl_xor(mx, 32));

        // ---- defer-max online softmax (T13) ----
        const bool skip = (mx <= m_run + 11.0f);
        if (!__all(skip)) {
            const float mnew = fmaxf(m_run, mx);
            const float alpha = exp2f(m_run - mnew);
            m_run = mnew;
            l_run *= alpha;
            #pragma unroll
            for (int r = 0; r < 16; ++r) {
                const float ar = __shfl(alpha, (r&3) + 8*(r>>2) + 4*hi);
                #pragma unroll
                for (int n = 0; n < 4; ++n) oacc[n][r] *= ar;
            }
        }

        float rs = 0.f;
        #pragma unroll
        for (int r = 0; r < 16; ++r) {
            s0[r] = exp2f(s0[r] - m_run);
            s1[r] = exp2f(s1[r] - m_run);
            rs += s0[r] + s1[r];
        }
        rs += __shfl_xor(rs, 32);
        l_run += rs;

        // ---- pack P -> bf16 dwords (cvt_pk), exchange halves (shfl_xor) ----
        uint32_t u0[8], u1[8], w0[8], w1[8];
        #pragma unroll
        for (int i = 0; i < 8; ++i) {
            u0[i] = cvtpk_bf16(s0[2*i], s0[2*i+1]);
            u1[i] = cvtpk_bf16(s1[2*i], s1[2*i+1]);
        }
        #pragma unroll
        for (int i = 0; i < 8; ++i) {
            w0[i] = __shfl_xor(u0[i], 32);
            w1[i] = __shfl_xor(u1[i], 32);
        }
        union PF { uint32_t d[4]; short8 s8; };
        PF pa[4];
        pa[0].d[0] = hi ? w0[2] : u0[0];  pa[0].d[1] = hi ? w0[3] : u0[1];
        pa[0].d[2] = hi ? u0[2] : w0[0];  pa[0].d[3] = hi ? u0[3] : w0[1];
        pa[1].d[0] = hi ? w0[6] : u0[4];  pa[1].d[1] = hi ? w0[7] : u0[5];
        pa[1].d[2] = hi ? u0[6] : w0[4];  pa[1].d[3] = hi ? u0[7] : w0[5];
        pa[2].d[0] = hi ? w1[2] : u1[0];  pa[2].d[1] = hi ? w1[3] : u1[1];
        pa[2].d[2] = hi ? u1[2] : w1[0];  pa[2].d[3] = hi ? u1[3] : w1[1];
        pa[3].d[0] = hi ? w1[6] : u1[4];  pa[3].d[1] = hi ? w1[7] : u1[5];
        pa[3].d[2] = hi ? u1[6] : w1[4];  pa[3].d[3] = hi ? u1[7] : w1[5];

        // ---- PV: oacc[n] over d-blocks, k-slots 0..3 ----
        __builtin_amdgcn_s_setprio(1);
        #pragma unroll
        for (int ks = 0; ks < 4; ++ks) {
            #pragma unroll
            for (int n = 0; n < 4; ++n) {
                const int d = n*32 + l31;
                const int colv = (ks*16 + hi*8) ^ ((l31 & 7) << 3);
                short8 vf = *(const short8*)&VT[d * 64 + colv];
                oacc[n] = __builtin_amdgcn_mfma_f32_32x32x16_bf16(pa[ks].s8, vf, oacc[n], 0, 0, 0);
            }
        }
        __builtin_amdgcn_s_setprio(0);
    }

    // ---- epilogue: O[qrow(reg)][d(col)] / l ----
    const float linv = 1.f / l_run;
    #pragma unroll
    for (int r = 0; r < 16; ++r) {
        const int qr = (r&3) + 8*(r>>2) + 4*hi;
        const float lr = __shfl(linv, qr);
        const size_t row = (size_t)(b * kS) + blockIdx.x * 128 + w * 32 + qr;
        #pragma unroll
        for (int n = 0; n < 4; ++n)
            o[row * kDim + h * kHd + n*32 + l31] = f2bf(oacc[n][r] * lr);
    }
}

// ---------------------------------------------------------------------------
extern "C" void kernel_launch(void* const* d_in, const int* in_sizes, int n_in,
                              void* d_out, int out_size, void* d_ws, size_t ws_size,
                              hipStream_t stream)
{
    (void)in_sizes; (void)n_in; (void)out_size; (void)ws_size;
    const float* x          = (const float*)d_in[0];
    const int*   seq_lens   = (const int*)  d_in[1];
    const int*   grid_sizes = (const int*)  d_in[2];
    const float* freqs      = (const float*)d_in[3];
    const float* Wq = (const float*)d_in[4];
    const float* bq = (const float*)d_in[5];
    const float* Wk = (const float*)d_in[6];
    const float* bk = (const float*)d_in[7];
    const float* Wv = (const float*)d_in[8];
    const float* bv = (const float*)d_in[9];
    const float* Wo = (const float*)d_in[10];
    const float* bo = (const float*)d_in[11];
    const float* gq = (const float*)d_in[12];
    const float* gk = (const float*)d_in[13];
    float* out = (float*)d_out;

    const int M = kB * kS;                       // 6144
    const size_t szX = (size_t)M * kDim;
    const size_t szW = (size_t)kDim * kDim;

    ushort* xb  = (ushort*)d_ws;
    ushort* wqb = xb  + szX;
    ushort* wkb = wqb + szW;
    ushort* wvb = wkb + szW;
    ushort* wob = wvb + szW;
    ushort* qb  = wob + szW;
    ushort* kbf = qb  + szX;
    ushort* vbf = kbf + szX;
    ushort* ab  = vbf + szX;
    ushort* vtb = ab  + szX;

    dim3 blk(256);
    cvt_kernel<<<dim3((int)(szX/8/256)), blk, 0, stream>>>(x,  xb,  (int)(szX/8));
    cvt_kernel<<<dim3((int)(szW/8/256)), blk, 0, stream>>>(Wq, wqb, (int)(szW/8));
    cvt_kernel<<<dim3((int)(szW/8/256)), blk, 0, stream>>>(Wk, wkb, (int)(szW/8));
    cvt_kernel<<<dim3((int)(szW/8/256)), blk, 0, stream>>>(Wv, wvb, (int)(szW/8));
    cvt_kernel<<<dim3((int)(szW/8/256)), blk, 0, stream>>>(Wo, wob, (int)(szW/8));

    dim3 gg(kDim / 128, M / 128);                // (12, 48)
    gemm_bf16<ushort><<<gg, blk, 0, stream>>>(xb, wqb, bq, qb,  M, kDim, kDim);
    gemm_bf16<ushort><<<gg, blk, 0, stream>>>(xb, wkb, bk, kbf, M, kDim, kDim);
    gemm_bf16<ushort><<<gg, blk, 0, stream>>>(xb, wvb, bv, vbf, M, kDim, kDim);

    vtrans_kernel<<<dim3(kS/64, 2, kB*kHeads), blk, 0, stream>>>(vbf, vtb);
    rmsrope_kernel<<<dim3(M, 2), dim3(192), 0, stream>>>(qb, kbf, gq, gk, freqs, grid_sizes);

    attn_kernel<<<dim3(kS/128, kHeads, kB), blk, 0, stream>>>(qb, kbf, vtb, ab, seq_lens);

    gemm_bf16<float><<<gg, blk, 0, stream>>>(ab, wob, bo, out, M, kDim, kDim);
}